// Round 1
// 298.414 us; speedup vs baseline: 1.0612x; 1.0612x over previous
//
#include <hip/hip_runtime.h>

#define NF 128   // FEATURE == HIDDEN
#define NC 64    // CLASSES
#define NBA 640  // pass-A blocks
#define NBKT 196 // ceil(100000/512) coarse buckets

typedef short short8 __attribute__((ext_vector_type(8)));
typedef unsigned short ushort;
typedef float f32x4 __attribute__((ext_vector_type(4)));
typedef float f32x2 __attribute__((ext_vector_type(2)));
typedef unsigned int uint;
typedef unsigned char uchar;

__device__ __forceinline__ ushort f2b(float x) {  // RNE float->bf16
  unsigned u = __builtin_bit_cast(unsigned, x);
  u += 0x7fffu + ((u >> 16) & 1u);
  return (ushort)(u >> 16);
}

// ---------------- fused prep: cast x->bf16+fp8, pack W1/W2, edge histogram --
__global__ __launch_bounds__(256) void prep_kernel(
    const float* __restrict__ x, ushort* __restrict__ xb,
    uchar* __restrict__ x8, int n4, int nb_cast,
    const float* __restrict__ W1l, const float* __restrict__ W1r,
    ushort* __restrict__ Wp1,
    const float* __restrict__ W2l, const float* __restrict__ W2r,
    ushort* __restrict__ Wp2l, ushort* __restrict__ Wp2r,
    const int* __restrict__ dst, int* __restrict__ cntA, int nE, int epb) {
  __shared__ int lh[NBKT];
  int b = blockIdx.x;
  if (b < nb_cast) {
    int i = b * 256 + threadIdx.x;
    if (i >= n4) return;
    float4 v = ((const float4*)x)[i];
    ushort4 o;
    o.x = f2b(v.x); o.y = f2b(v.y); o.z = f2b(v.z); o.w = f2b(v.w);
    ((ushort4*)xb)[i] = o;
    int u = __builtin_amdgcn_cvt_pk_fp8_f32(v.x, v.y, 0, false);
    u = __builtin_amdgcn_cvt_pk_fp8_f32(v.z, v.w, u, true);
    ((uint*)x8)[i] = (uint)u;
  } else if (b < nb_cast + 128) {
    int tid = (b - nb_cast) * 256 + threadIdx.x;  // 0..32767
    int j = tid & 7;
    int lane = (tid >> 3) & 63;
    int tile = tid >> 9;
    int nt = tile & 7, kt = tile >> 3;
    int k = kt * 32 + ((lane >> 4) << 3) + j;
    int n = nt * 16 + (lane & 15);
    float v = (k < 128) ? W1l[n * 128 + k] : W1r[n * 128 + (k - 128)];
    Wp1[tid] = f2b(v);
  } else if (b < nb_cast + 192) {
    int tid0 = (b - nb_cast - 128) * 256 + threadIdx.x;  // 0..16383
    int which = tid0 >> 13;
    int tid = tid0 & 8191;
    int j = tid & 7;
    int lane = (tid >> 3) & 63;
    int tile = tid >> 9;
    int nt = tile & 3, kt = tile >> 2;
    int k = kt * 32 + ((lane >> 4) << 3) + j;
    int n = nt * 16 + (lane & 15);
    const float* W = which ? W2r : W2l;
    ushort* Wp = which ? Wp2r : Wp2l;
    Wp[tid] = f2b(W[n * 128 + k]);
  } else {
    // per-block coarse histogram of dst (was bhistA_kernel)
    int blk = b - nb_cast - 192;
    const int t = threadIdx.x;
    for (int i = t; i < NBKT; i += 256) lh[i] = 0;
    __syncthreads();
    int s0 = blk * epb, s1 = min(nE, s0 + epb);
    for (int e = s0 + t; e < s1; e += 256) atomicAdd(&lh[dst[e] >> 9], 1);
    __syncthreads();
    for (int i = t; i < NBKT; i += 256)
      cntA[(size_t)i * NBA + blk] = lh[i];
  }
}

// ---------------- generic exclusive scan (2 kernels) over L <= 131072 -------
// scanL1 produces per-1024-chunk exclusive scans + chunk sums; scanL2 scans
// the chunk sums in place. Consumers add bsum[idx>>10] inline (scanL3 removed).
__global__ __launch_bounds__(256) void scanL1_kernel(const int* __restrict__ in,
                                                     int* __restrict__ out,
                                                     int* __restrict__ bsum, int L) {
  const int t = threadIdx.x;
  const int base = blockIdx.x * 1024 + t * 4;
  int v[4];
  int tsum = 0;
#pragma unroll
  for (int k = 0; k < 4; ++k) {
    v[k] = (base + k < L) ? in[base + k] : 0;
    tsum += v[k];
  }
  int lane = t & 63, wid = t >> 6;
  int x = tsum;
#pragma unroll
  for (int d = 1; d < 64; d <<= 1) {
    int y = __shfl_up(x, d);
    if (lane >= d) x += y;
  }
  __shared__ int wsum[4];
  if (lane == 63) wsum[wid] = x;
  __syncthreads();
  int wbase = 0;
  for (int w = 0; w < wid; ++w) wbase += wsum[w];
  int run = wbase + x - tsum;
#pragma unroll
  for (int k = 0; k < 4; ++k) {
    if (base + k < L) out[base + k] = run;
    run += v[k];
  }
  if (t == 0) bsum[blockIdx.x] = wsum[0] + wsum[1] + wsum[2] + wsum[3];
}

__global__ void scanL2_kernel(int* __restrict__ bsum, int nb) {
  int lane = threadIdx.x;
  int i0 = 2 * lane, i1 = 2 * lane + 1;
  int v0 = (i0 < nb) ? bsum[i0] : 0;
  int v1 = (i1 < nb) ? bsum[i1] : 0;
  int s = v0 + v1;
  int x = s;
#pragma unroll
  for (int d = 1; d < 64; d <<= 1) {
    int y = __shfl_up(x, d);
    if (lane >= d) x += y;
  }
  int ex = x - s;
  if (i0 < nb) bsum[i0] = ex;
  if (i1 < nb) bsum[i1] = ex + v0;
}

// ---------------- CSR build pass A3: scatter into coarse buckets ------------
// tmp entry: (dst & 511) << 17 | src   (26 bits)
__global__ __launch_bounds__(256) void bscatA_kernel(const int* __restrict__ src,
                                                     const int* __restrict__ dst,
                                                     const int* __restrict__ cntS,
                                                     const int* __restrict__ bsum,
                                                     uint* __restrict__ tmp,
                                                     int nE, int epb) {
  __shared__ int base[NBKT];
  __shared__ int cur[NBKT];
  const int t = threadIdx.x;
  for (int i = t; i < NBKT; i += 256) {
    size_t idx = (size_t)i * NBA + blockIdx.x;
    base[i] = cntS[idx] + bsum[idx >> 10];
    cur[i] = 0;
  }
  __syncthreads();
  int s0 = blockIdx.x * epb, s1 = min(nE, s0 + epb);
  for (int e = s0 + t; e < s1; e += 256) {
    int d = dst[e];
    int s = src[e];
    int b = d >> 9;
    int r = atomicAdd(&cur[b], 1);
    tmp[base[b] + r] = ((uint)(d & 511) << 17) | (uint)s;
  }
}

// ---------------- CSR build pass B: per-bucket node sort + deg/off ----------
__global__ __launch_bounds__(256) void bsortB_kernel(const uint* __restrict__ tmp,
                                                     const int* __restrict__ cntS,
                                                     const int* __restrict__ bsum,
                                                     int* __restrict__ esrc,
                                                     int* __restrict__ deg,
                                                     int* __restrict__ off,
                                                     int nN, int nE) {
  const int bkt = blockIdx.x;
  const int t = threadIdx.x;
  __shared__ int lh[512];
  __shared__ int cur[512];
  __shared__ int wsum[4];
  const size_t ia = (size_t)bkt * NBA;
  const int start = cntS[ia] + bsum[ia >> 10];
  int end;
  if (bkt + 1 < NBKT) {
    const size_t ib = (size_t)(bkt + 1) * NBA;
    end = cntS[ib] + bsum[ib >> 10];
  } else {
    end = nE;
  }
  lh[t] = 0;
  lh[t + 256] = 0;
  __syncthreads();
  for (int i = start + t; i < end; i += 256) {
    uint e = tmp[i];
    atomicAdd(&lh[e >> 17], 1);
  }
  __syncthreads();
  int v0 = lh[2 * t], v1 = lh[2 * t + 1];
  int ts = v0 + v1;
  int lane = t & 63, wid = t >> 6;
  int x = ts;
#pragma unroll
  for (int d = 1; d < 64; d <<= 1) {
    int y = __shfl_up(x, d);
    if (lane >= d) x += y;
  }
  if (lane == 63) wsum[wid] = x;
  __syncthreads();
  int wb = 0;
  for (int w = 0; w < wid; ++w) wb += wsum[w];
  int ex = wb + x - ts;
  cur[2 * t] = ex;
  cur[2 * t + 1] = ex + v0;
  int n0 = (bkt << 9) + 2 * t, n1 = n0 + 1;
  if (n0 < nN) { off[n0] = start + ex;      deg[n0] = v0; }
  if (n1 < nN) { off[n1] = start + ex + v0; deg[n1] = v1; }
  __syncthreads();
  for (int i = start + t; i < end; i += 256) {
    uint e = tmp[i];
    int r = atomicAdd(&cur[e >> 17], 1);
    esrc[start + r] = (int)(e & 0x1FFFFu);
  }
}

// ---------------- gather 1 (fp8 in, bf16 out, 128-dim rows) -----------------
// one wave per node; 8 lane-groups of 8 lanes, 16B/lane loads, 16 edges in
// flight per unrolled iteration (2 row-loads per lane).
__global__ __launch_bounds__(256) void gather1_kernel(
    const uchar* __restrict__ x8, const int* __restrict__ esrc,
    const int* __restrict__ off, const int* __restrict__ deg,
    ushort* __restrict__ aggm, int nN) {
  const int w = (blockIdx.x * blockDim.x + threadIdx.x) >> 6;
  const int lane = threadIdx.x & 63;
  if (w >= nN) return;
  const int o = off[w];
  const int d = deg[w];
  const int g = lane >> 3;
  const int l = lane & 7;
  f32x2 acc[8] = {};
  int i = 0;
  for (; i + 16 <= d; i += 16) {
    int sA = esrc[o + i + g];
    int sB = esrc[o + i + 8 + g];
    uint4 vA = ((const uint4*)(x8 + (size_t)sA * NF))[l];
    uint4 vB = ((const uint4*)(x8 + (size_t)sB * NF))[l];
    acc[0] += __builtin_amdgcn_cvt_pk_f32_fp8(vA.x, false) +
              __builtin_amdgcn_cvt_pk_f32_fp8(vB.x, false);
    acc[1] += __builtin_amdgcn_cvt_pk_f32_fp8(vA.x, true) +
              __builtin_amdgcn_cvt_pk_f32_fp8(vB.x, true);
    acc[2] += __builtin_amdgcn_cvt_pk_f32_fp8(vA.y, false) +
              __builtin_amdgcn_cvt_pk_f32_fp8(vB.y, false);
    acc[3] += __builtin_amdgcn_cvt_pk_f32_fp8(vA.y, true) +
              __builtin_amdgcn_cvt_pk_f32_fp8(vB.y, true);
    acc[4] += __builtin_amdgcn_cvt_pk_f32_fp8(vA.z, false) +
              __builtin_amdgcn_cvt_pk_f32_fp8(vB.z, false);
    acc[5] += __builtin_amdgcn_cvt_pk_f32_fp8(vA.z, true) +
              __builtin_amdgcn_cvt_pk_f32_fp8(vB.z, true);
    acc[6] += __builtin_amdgcn_cvt_pk_f32_fp8(vA.w, false) +
              __builtin_amdgcn_cvt_pk_f32_fp8(vB.w, false);
    acc[7] += __builtin_amdgcn_cvt_pk_f32_fp8(vA.w, true) +
              __builtin_amdgcn_cvt_pk_f32_fp8(vB.w, true);
  }
  for (; i + 8 <= d; i += 8) {
    int s = esrc[o + i + g];
    uint4 v = ((const uint4*)(x8 + (size_t)s * NF))[l];
    acc[0] += __builtin_amdgcn_cvt_pk_f32_fp8(v.x, false);
    acc[1] += __builtin_amdgcn_cvt_pk_f32_fp8(v.x, true);
    acc[2] += __builtin_amdgcn_cvt_pk_f32_fp8(v.y, false);
    acc[3] += __builtin_amdgcn_cvt_pk_f32_fp8(v.y, true);
    acc[4] += __builtin_amdgcn_cvt_pk_f32_fp8(v.z, false);
    acc[5] += __builtin_amdgcn_cvt_pk_f32_fp8(v.z, true);
    acc[6] += __builtin_amdgcn_cvt_pk_f32_fp8(v.w, false);
    acc[7] += __builtin_amdgcn_cvt_pk_f32_fp8(v.w, true);
  }
  if (i + g < d) {
    int s = esrc[o + i + g];
    uint4 v = ((const uint4*)(x8 + (size_t)s * NF))[l];
    acc[0] += __builtin_amdgcn_cvt_pk_f32_fp8(v.x, false);
    acc[1] += __builtin_amdgcn_cvt_pk_f32_fp8(v.x, true);
    acc[2] += __builtin_amdgcn_cvt_pk_f32_fp8(v.y, false);
    acc[3] += __builtin_amdgcn_cvt_pk_f32_fp8(v.y, true);
    acc[4] += __builtin_amdgcn_cvt_pk_f32_fp8(v.z, false);
    acc[5] += __builtin_amdgcn_cvt_pk_f32_fp8(v.z, true);
    acc[6] += __builtin_amdgcn_cvt_pk_f32_fp8(v.w, false);
    acc[7] += __builtin_amdgcn_cvt_pk_f32_fp8(v.w, true);
  }
  float r[16];
#pragma unroll
  for (int k = 0; k < 8; ++k) { r[2 * k] = acc[k].x; r[2 * k + 1] = acc[k].y; }
#pragma unroll
  for (int k = 0; k < 16; ++k) {
    r[k] += __shfl_xor(r[k], 8);
    r[k] += __shfl_xor(r[k], 16);
    r[k] += __shfl_xor(r[k], 32);
  }
  if (g == 0) {
    float inv = 1.0f / fmaxf((float)d, 1.0f);
    uint4 o0, o1;
    o0.x = (uint)f2b(r[0] * inv)  | ((uint)f2b(r[1] * inv) << 16);
    o0.y = (uint)f2b(r[2] * inv)  | ((uint)f2b(r[3] * inv) << 16);
    o0.z = (uint)f2b(r[4] * inv)  | ((uint)f2b(r[5] * inv) << 16);
    o0.w = (uint)f2b(r[6] * inv)  | ((uint)f2b(r[7] * inv) << 16);
    o1.x = (uint)f2b(r[8] * inv)  | ((uint)f2b(r[9] * inv) << 16);
    o1.y = (uint)f2b(r[10] * inv) | ((uint)f2b(r[11] * inv) << 16);
    o1.z = (uint)f2b(r[12] * inv) | ((uint)f2b(r[13] * inv) << 16);
    o1.w = (uint)f2b(r[14] * inv) | ((uint)f2b(r[15] * inv) << 16);
    ((uint4*)(aggm + (size_t)w * NF))[2 * l] = o0;
    ((uint4*)(aggm + (size_t)w * NF))[2 * l + 1] = o1;
  }
}

// ---------------- gather 2 (fp8 in, fp32 out, 64-dim rows, permuted) --------
// z8 row layout: byte (cl*4 + nt) holds logical col (nt*16 + cl).
// aggz keeps the same permuted layout; layer2b consumes it as float4 per cl.
__global__ __launch_bounds__(256) void gather2_kernel(
    const uchar* __restrict__ z8, const int* __restrict__ esrc,
    const int* __restrict__ off, const int* __restrict__ deg,
    float* __restrict__ aggz, int nN) {
  const int w = (blockIdx.x * blockDim.x + threadIdx.x) >> 6;
  const int lane = threadIdx.x & 63;
  if (w >= nN) return;
  const int o = off[w];
  const int d = deg[w];
  const int g = lane >> 3;
  const int l = lane & 7;
  f32x2 acc[4] = {};
  int i = 0;
  for (; i + 16 <= d; i += 16) {
    int sA = esrc[o + i + g];
    int sB = esrc[o + i + 8 + g];
    uint2 vA = ((const uint2*)(z8 + (size_t)sA * NC))[l];
    uint2 vB = ((const uint2*)(z8 + (size_t)sB * NC))[l];
    acc[0] += __builtin_amdgcn_cvt_pk_f32_fp8(vA.x, false) +
              __builtin_amdgcn_cvt_pk_f32_fp8(vB.x, false);
    acc[1] += __builtin_amdgcn_cvt_pk_f32_fp8(vA.x, true) +
              __builtin_amdgcn_cvt_pk_f32_fp8(vB.x, true);
    acc[2] += __builtin_amdgcn_cvt_pk_f32_fp8(vA.y, false) +
              __builtin_amdgcn_cvt_pk_f32_fp8(vB.y, false);
    acc[3] += __builtin_amdgcn_cvt_pk_f32_fp8(vA.y, true) +
              __builtin_amdgcn_cvt_pk_f32_fp8(vB.y, true);
  }
  for (; i + 8 <= d; i += 8) {
    int s = esrc[o + i + g];
    uint2 v = ((const uint2*)(z8 + (size_t)s * NC))[l];
    acc[0] += __builtin_amdgcn_cvt_pk_f32_fp8(v.x, false);
    acc[1] += __builtin_amdgcn_cvt_pk_f32_fp8(v.x, true);
    acc[2] += __builtin_amdgcn_cvt_pk_f32_fp8(v.y, false);
    acc[3] += __builtin_amdgcn_cvt_pk_f32_fp8(v.y, true);
  }
  if (i + g < d) {
    int s = esrc[o + i + g];
    uint2 v = ((const uint2*)(z8 + (size_t)s * NC))[l];
    acc[0] += __builtin_amdgcn_cvt_pk_f32_fp8(v.x, false);
    acc[1] += __builtin_amdgcn_cvt_pk_f32_fp8(v.x, true);
    acc[2] += __builtin_amdgcn_cvt_pk_f32_fp8(v.y, false);
    acc[3] += __builtin_amdgcn_cvt_pk_f32_fp8(v.y, true);
  }
  float r[8] = {acc[0].x, acc[0].y, acc[1].x, acc[1].y,
                acc[2].x, acc[2].y, acc[3].x, acc[3].y};
#pragma unroll
  for (int k = 0; k < 8; ++k) {
    r[k] += __shfl_xor(r[k], 8);
    r[k] += __shfl_xor(r[k], 16);
    r[k] += __shfl_xor(r[k], 32);
  }
  if (g == 0) {
    float inv = 1.0f / fmaxf((float)d, 1.0f);
    ((float4*)(aggz + (size_t)w * NC))[2 * l] =
        make_float4(r[0] * inv, r[1] * inv, r[2] * inv, r[3] * inv);
    ((float4*)(aggz + (size_t)w * NC))[2 * l + 1] =
        make_float4(r[4] * inv, r[5] * inv, r[6] * inv, r[7] * inv);
  }
}

// ---------------- fused layer 1 + 2a (MFMA) ---------------------------------
// h = relu([mean||x] @ W1cat + b1)   -> hb (global, bf16) and LDS band
// z = h @ W2l^T                      -> z8 (fp8, permuted layout)
// Each wave writes h only into the 16 LDS rows it alone reads for the second
// MFMA stage, so no extra __syncthreads is needed between the stages.
__global__ __launch_bounds__(256) void layer12_mfma(
    const ushort* __restrict__ xb, const ushort* __restrict__ aggb,
    const ushort* __restrict__ Wp1, const float* __restrict__ b1,
    const ushort* __restrict__ Wp2l,
    ushort* __restrict__ hb, uchar* __restrict__ z8, int nN) {
  const int t = threadIdx.x;
  const int wv = t >> 6;
  const int lane = t & 63;
  const int base = blockIdx.x * 64;
  __shared__ ushort As[64][264];  // 256 cols + 8 pad
  for (int i = t; i < 64 * 32; i += 256) {
    int r = i >> 5, cq = i & 31;
    int node = base + r;
    short8 v = {};
    if (node < nN) {
      const ushort* sp = (cq < 16) ? (aggb + (size_t)node * NF + cq * 8)
                                   : (xb + (size_t)node * NF + (cq - 16) * 8);
      v = *(const short8*)sp;
    }
    *(short8*)&As[r][cq * 8] = v;
  }
  __syncthreads();

  f32x4 acc[8] = {};
  const int arow = wv * 16 + (lane & 15);
  const int kq = (lane >> 4) * 8;
#pragma unroll
  for (int kt = 0; kt < 8; ++kt) {
    short8 af = *(const short8*)&As[arow][kt * 32 + kq];
#pragma unroll
    for (int nt = 0; nt < 8; ++nt) {
      short8 bf = *(const short8*)(Wp1 + ((size_t)(kt * 8 + nt) * 64 + lane) * 8);
      acc[nt] = __builtin_amdgcn_mfma_f32_16x16x32_bf16(af, bf, acc[nt], 0, 0, 0);
    }
  }
  const int quad = lane >> 4;
  const int cl = lane & 15;
#pragma unroll
  for (int nt = 0; nt < 8; ++nt) {
    float bj = b1[nt * 16 + cl];
#pragma unroll
    for (int r = 0; r < 4; ++r) {
      int node = base + wv * 16 + quad * 4 + r;
      ushort hv = f2b(fmaxf(acc[nt][r] + bj, 0.0f));
      As[wv * 16 + quad * 4 + r][nt * 16 + cl] = hv;  // wave-private band
      if (node < nN) hb[(size_t)node * NF + nt * 16 + cl] = hv;
    }
  }

  // ---- stage 2: z = h @ W2l^T (reads only this wave's own LDS band) ----
  f32x4 acc2[4] = {};
#pragma unroll
  for (int kt = 0; kt < 4; ++kt) {
    short8 af = *(const short8*)&As[arow][kt * 32 + kq];
#pragma unroll
    for (int nt = 0; nt < 4; ++nt) {
      short8 bf = *(const short8*)(Wp2l + ((size_t)(kt * 4 + nt) * 64 + lane) * 8);
      acc2[nt] = __builtin_amdgcn_mfma_f32_16x16x32_bf16(af, bf, acc2[nt], 0, 0, 0);
    }
  }
#pragma unroll
  for (int r = 0; r < 4; ++r) {
    int node = base + wv * 16 + quad * 4 + r;
    if (node < nN) {
      int u = __builtin_amdgcn_cvt_pk_fp8_f32(acc2[0][r], acc2[1][r], 0, false);
      u = __builtin_amdgcn_cvt_pk_fp8_f32(acc2[2][r], acc2[3][r], u, true);
      ((uint*)(z8 + (size_t)node * NC))[cl] = (uint)u;
    }
  }
}

// ---------------- layer 2b (MFMA): out = logsoftmax(aggz + h@W2r^T + b) -----
__global__ __launch_bounds__(256) void layer2b_mfma(
    const ushort* __restrict__ hb, const float* __restrict__ aggz,
    const ushort* __restrict__ Wp, const float* __restrict__ b2,
    float* __restrict__ out, int nN) {
  const int t = threadIdx.x;
  const int wv = t >> 6;
  const int lane = t & 63;
  const int base = blockIdx.x * 64;
  __shared__ ushort As[64][136];
  for (int i = t; i < 64 * 16; i += 256) {
    int r = i >> 4, cq = i & 15;
    int node = base + r;
    short8 v = {};
    if (node < nN) v = *(const short8*)(hb + (size_t)node * NF + cq * 8);
    *(short8*)&As[r][cq * 8] = v;
  }
  __syncthreads();

  f32x4 acc[4] = {};
  const int arow = wv * 16 + (lane & 15);
  const int kq = (lane >> 4) * 8;
#pragma unroll
  for (int kt = 0; kt < 4; ++kt) {
    short8 af = *(const short8*)&As[arow][kt * 32 + kq];
#pragma unroll
    for (int nt = 0; nt < 4; ++nt) {
      short8 bf = *(const short8*)(Wp + ((size_t)(kt * 4 + nt) * 64 + lane) * 8);
      acc[nt] = __builtin_amdgcn_mfma_f32_16x16x32_bf16(af, bf, acc[nt], 0, 0, 0);
    }
  }
  const int quad = lane >> 4;
  const int cl = lane & 15;
  float bj[4];
#pragma unroll
  for (int nt = 0; nt < 4; ++nt) bj[nt] = b2[nt * 16 + cl];

#pragma unroll
  for (int r = 0; r < 4; ++r) {
    int node = base + wv * 16 + quad * 4 + r;
    int nvalid = (node < nN);
    float a0 = 0.f, a1 = 0.f, a2 = 0.f, a3 = 0.f;
    if (nvalid) {
      // aggz is in the permuted layout: float4 at [cl] = cols {nt*16+cl}
      float4 av = ((const float4*)(aggz + (size_t)node * NC))[cl];
      a0 = av.x; a1 = av.y; a2 = av.z; a3 = av.w;
    }
    float v0 = acc[0][r] + bj[0] + a0;
    float v1 = acc[1][r] + bj[1] + a1;
    float v2 = acc[2][r] + bj[2] + a2;
    float v3 = acc[3][r] + bj[3] + a3;
    float mx = fmaxf(fmaxf(v0, v1), fmaxf(v2, v3));
#pragma unroll
    for (int s = 1; s < 16; s <<= 1) mx = fmaxf(mx, __shfl_xor(mx, s));
    float sm = expf(v0 - mx) + expf(v1 - mx) + expf(v2 - mx) + expf(v3 - mx);
#pragma unroll
    for (int s = 1; s < 16; s <<= 1) sm += __shfl_xor(sm, s);
    float ls = mx + logf(sm);
    if (nvalid) {
      float* op = out + (size_t)node * NC;
      op[0 * 16 + cl] = v0 - ls;
      op[1 * 16 + cl] = v1 - ls;
      op[2 * 16 + cl] = v2 - ls;
      op[3 * 16 + cl] = v3 - ls;
    }
  }
}

extern "C" void kernel_launch(void* const* d_in, const int* in_sizes, int n_in,
                              void* d_out, int out_size, void* d_ws, size_t ws_size,
                              hipStream_t stream) {
  const float* x   = (const float*)d_in[0];
  const int*   ei  = (const int*)d_in[1];
  const float* W1l = (const float*)d_in[2];
  const float* b1l = (const float*)d_in[3];
  const float* W1r = (const float*)d_in[4];
  const float* W2l = (const float*)d_in[5];
  const float* b2l = (const float*)d_in[6];
  const float* W2r = (const float*)d_in[7];
  float* out = (float*)d_out;

  const int nN = in_sizes[0] / NF;  // 100000
  const int nE = in_sizes[1] / 2;   // 1600000
  const int* src = ei;
  const int* dst = ei + nE;

  char* p = (char*)d_ws;
  ushort* xb   = (ushort*)p; p += (size_t)nN * NF * 2;
  ushort* hb   = (ushort*)p; p += (size_t)nN * NF * 2;   // first half doubles as x8
  ushort* aggb = (ushort*)p; p += (size_t)nN * NF * 2;   // reused as aggz (fp32, same bytes)
  ushort* Wp1  = (ushort*)p; p += 256 * 128 * 2;
  ushort* Wp2l = (ushort*)p; p += 128 * 64 * 2;
  ushort* Wp2r = (ushort*)p; p += 128 * 64 * 2;
  int* cntA = (int*)p; p += (size_t)NBKT * NBA * 4;
  int* cntS = (int*)p; p += (size_t)NBKT * NBA * 4;
  int* bsum = (int*)p; p += 512;
  int* deg  = (int*)p; p += (size_t)nN * 4;
  int* off  = (int*)p; p += (size_t)nN * 4;
  int* esrc = (int*)p; p += (size_t)nE * 4;
  uint* tmp = (uint*)p; p += (size_t)nE * 4;             // doubles as z8 after bsortB

  uchar* x8   = (uchar*)hb;     // alias: hb written only in layer12, after gather1
  uchar* z8   = (uchar*)tmp;    // alias: tmp dead after bsortB
  float* aggz = (float*)aggb;   // alias: aggb dead after layer12

  const int n4 = nN * NF / 4;
  const int nb_cast = (n4 + 255) / 256;
  const int epb = (nE + NBA - 1) / NBA;
  const int L = NBKT * NBA;
  const int nbL = (L + 1023) / 1024;

  // prep (casts + weight packs) + edge histogram fused into one launch
  prep_kernel<<<nb_cast + 192 + NBA, 256, 0, stream>>>(
      x, xb, x8, n4, nb_cast, W1l, W1r, Wp1, W2l, W2r, Wp2l, Wp2r,
      dst, cntA, nE, epb);

  // --- CSR build: atomic-free (LDS-only ranks) two-pass bucket sort ---
  scanL1_kernel<<<nbL, 256, 0, stream>>>(cntA, cntS, bsum, L);
  scanL2_kernel<<<1, 64, 0, stream>>>(bsum, nbL);
  bscatA_kernel<<<NBA, 256, 0, stream>>>(src, dst, cntS, bsum, tmp, nE, epb);
  bsortB_kernel<<<NBKT, 256, 0, stream>>>(tmp, cntS, bsum, esrc, deg, off, nN, nE);

  // --- layer 1 + 2a ---
  gather1_kernel<<<(nN + 3) / 4, 256, 0, stream>>>(x8, esrc, off, deg, aggb, nN);
  layer12_mfma<<<(nN + 63) / 64, 256, 0, stream>>>(xb, aggb, Wp1, b1l, Wp2l, hb, z8, nN);

  // --- layer 2 (projection-first: mean of z, then +h@W2r) ---
  gather2_kernel<<<(nN + 3) / 4, 256, 0, stream>>>(z8, esrc, off, deg, aggz, nN);
  layer2b_mfma<<<(nN + 63) / 64, 256, 0, stream>>>(hb, aggz, Wp2r, b2l, out, nN);
}

// Round 2
// 265.728 us; speedup vs baseline: 1.1917x; 1.1230x over previous
//
#include <hip/hip_runtime.h>

#define NF 128   // FEATURE == HIDDEN
#define NC 64    // CLASSES
#define NBA 640  // pass-A blocks
#define NBKT 196 // ceil(100000/512) coarse buckets

typedef short short8 __attribute__((ext_vector_type(8)));
typedef unsigned short ushort;
typedef float f32x4 __attribute__((ext_vector_type(4)));
typedef float f32x2 __attribute__((ext_vector_type(2)));
typedef unsigned int uint;
typedef unsigned char uchar;

__device__ __forceinline__ ushort f2b(float x) {  // RNE float->bf16
  unsigned u = __builtin_bit_cast(unsigned, x);
  u += 0x7fffu + ((u >> 16) & 1u);
  return (ushort)(u >> 16);
}

// ---------------- fused prep: cast x->bf16+fp8, pack W1/W2, edge histogram --
__global__ __launch_bounds__(256) void prep_kernel(
    const float* __restrict__ x, ushort* __restrict__ xb,
    uchar* __restrict__ x8, int n4, int nb_cast,
    const float* __restrict__ W1l, const float* __restrict__ W1r,
    ushort* __restrict__ Wp1,
    const float* __restrict__ W2l, const float* __restrict__ W2r,
    ushort* __restrict__ Wp2l, ushort* __restrict__ Wp2r,
    const int* __restrict__ dst, int* __restrict__ cntA, int nE, int epb) {
  __shared__ int lh[NBKT];
  int b = blockIdx.x;
  if (b < nb_cast) {
    int i = b * 256 + threadIdx.x;
    if (i >= n4) return;
    float4 v = ((const float4*)x)[i];
    ushort4 o;
    o.x = f2b(v.x); o.y = f2b(v.y); o.z = f2b(v.z); o.w = f2b(v.w);
    ((ushort4*)xb)[i] = o;
    int u = __builtin_amdgcn_cvt_pk_fp8_f32(v.x, v.y, 0, false);
    u = __builtin_amdgcn_cvt_pk_fp8_f32(v.z, v.w, u, true);
    ((uint*)x8)[i] = (uint)u;
  } else if (b < nb_cast + 128) {
    int tid = (b - nb_cast) * 256 + threadIdx.x;  // 0..32767
    int j = tid & 7;
    int lane = (tid >> 3) & 63;
    int tile = tid >> 9;
    int nt = tile & 7, kt = tile >> 3;
    int k = kt * 32 + ((lane >> 4) << 3) + j;
    int n = nt * 16 + (lane & 15);
    float v = (k < 128) ? W1l[n * 128 + k] : W1r[n * 128 + (k - 128)];
    Wp1[tid] = f2b(v);
  } else if (b < nb_cast + 192) {
    int tid0 = (b - nb_cast - 128) * 256 + threadIdx.x;  // 0..16383
    int which = tid0 >> 13;
    int tid = tid0 & 8191;
    int j = tid & 7;
    int lane = (tid >> 3) & 63;
    int tile = tid >> 9;
    int nt = tile & 3, kt = tile >> 2;
    int k = kt * 32 + ((lane >> 4) << 3) + j;
    int n = nt * 16 + (lane & 15);
    const float* W = which ? W2r : W2l;
    ushort* Wp = which ? Wp2r : Wp2l;
    Wp[tid] = f2b(W[n * 128 + k]);
  } else {
    // per-block coarse histogram of dst
    int blk = b - nb_cast - 192;
    const int t = threadIdx.x;
    for (int i = t; i < NBKT; i += 256) lh[i] = 0;
    __syncthreads();
    int s0 = blk * epb, s1 = min(nE, s0 + epb);
    for (int e = s0 + t; e < s1; e += 256) atomicAdd(&lh[dst[e] >> 9], 1);
    __syncthreads();
    for (int i = t; i < NBKT; i += 256)
      cntA[(size_t)i * NBA + blk] = lh[i];
  }
}

// ---------------- scan L1: per-1024-chunk exclusive scans + raw chunk sums --
// Consumers (bscatA/bsortB) scan the <=128 chunk sums redundantly in-block.
__global__ __launch_bounds__(256) void scanL1_kernel(const int* __restrict__ in,
                                                     int* __restrict__ out,
                                                     int* __restrict__ bsum, int L) {
  const int t = threadIdx.x;
  const int base = blockIdx.x * 1024 + t * 4;
  int v[4];
  int tsum = 0;
#pragma unroll
  for (int k = 0; k < 4; ++k) {
    v[k] = (base + k < L) ? in[base + k] : 0;
    tsum += v[k];
  }
  int lane = t & 63, wid = t >> 6;
  int x = tsum;
#pragma unroll
  for (int d = 1; d < 64; d <<= 1) {
    int y = __shfl_up(x, d);
    if (lane >= d) x += y;
  }
  __shared__ int wsum[4];
  if (lane == 63) wsum[wid] = x;
  __syncthreads();
  int wbase = 0;
  for (int w = 0; w < wid; ++w) wbase += wsum[w];
  int run = wbase + x - tsum;
#pragma unroll
  for (int k = 0; k < 4; ++k) {
    if (base + k < L) out[base + k] = run;
    run += v[k];
  }
  if (t == 0) bsum[blockIdx.x] = wsum[0] + wsum[1] + wsum[2] + wsum[3];
}

// ---------------- CSR build pass A3: scatter into coarse buckets ------------
// tmp entry: (dst & 511) << 17 | src   (26 bits)
__global__ __launch_bounds__(256) void bscatA_kernel(const int* __restrict__ src,
                                                     const int* __restrict__ dst,
                                                     const int* __restrict__ cntS,
                                                     const int* __restrict__ bsum,
                                                     uint* __restrict__ tmp,
                                                     int nE, int epb, int nbL) {
  __shared__ int base[NBKT];
  __shared__ int cur[NBKT];
  __shared__ int sbs[128];
  __shared__ int w0s;
  const int t = threadIdx.x;
  // in-block exclusive scan of the <=128 raw chunk sums
  int ex = 0;
  if (t < 128) {
    int v = (t < nbL) ? bsum[t] : 0;
    int x = v;
#pragma unroll
    for (int d = 1; d < 64; d <<= 1) {
      int y = __shfl_up(x, d);
      if ((t & 63) >= d) x += y;
    }
    ex = x - v;
    if (t == 63) w0s = x;
  }
  __syncthreads();
  if (t < 128) sbs[t] = ex + ((t >= 64) ? w0s : 0);
  __syncthreads();
  for (int i = t; i < NBKT; i += 256) {
    size_t idx = (size_t)i * NBA + blockIdx.x;
    base[i] = cntS[idx] + sbs[idx >> 10];
    cur[i] = 0;
  }
  __syncthreads();
  int s0 = blockIdx.x * epb, s1 = min(nE, s0 + epb);
  for (int e = s0 + t; e < s1; e += 256) {
    int d = dst[e];
    int s = src[e];
    int b = d >> 9;
    int r = atomicAdd(&cur[b], 1);
    tmp[base[b] + r] = ((uint)(d & 511) << 17) | (uint)s;
  }
}

// ---------------- CSR build pass B: per-bucket node sort + deg/off ----------
__global__ __launch_bounds__(256) void bsortB_kernel(const uint* __restrict__ tmp,
                                                     const int* __restrict__ cntS,
                                                     const int* __restrict__ bsum,
                                                     int* __restrict__ esrc,
                                                     int* __restrict__ deg,
                                                     int* __restrict__ off,
                                                     int nN, int nE, int nbL) {
  const int bkt = blockIdx.x;
  const int t = threadIdx.x;
  __shared__ int lh[512];
  __shared__ int cur[512];
  __shared__ int wsum[4];
  __shared__ int sbs[128];
  __shared__ int w0s;
  // in-block exclusive scan of the <=128 raw chunk sums
  int ex0 = 0;
  if (t < 128) {
    int v = (t < nbL) ? bsum[t] : 0;
    int x = v;
#pragma unroll
    for (int d = 1; d < 64; d <<= 1) {
      int y = __shfl_up(x, d);
      if ((t & 63) >= d) x += y;
    }
    ex0 = x - v;
    if (t == 63) w0s = x;
  }
  __syncthreads();
  if (t < 128) sbs[t] = ex0 + ((t >= 64) ? w0s : 0);
  __syncthreads();
  const size_t ia = (size_t)bkt * NBA;
  const int start = cntS[ia] + sbs[ia >> 10];
  int end;
  if (bkt + 1 < NBKT) {
    const size_t ib = (size_t)(bkt + 1) * NBA;
    end = cntS[ib] + sbs[ib >> 10];
  } else {
    end = nE;
  }
  lh[t] = 0;
  lh[t + 256] = 0;
  __syncthreads();
  for (int i = start + t; i < end; i += 256) {
    uint e = tmp[i];
    atomicAdd(&lh[e >> 17], 1);
  }
  __syncthreads();
  int v0 = lh[2 * t], v1 = lh[2 * t + 1];
  int ts = v0 + v1;
  int lane = t & 63, wid = t >> 6;
  int x = ts;
#pragma unroll
  for (int d = 1; d < 64; d <<= 1) {
    int y = __shfl_up(x, d);
    if (lane >= d) x += y;
  }
  if (lane == 63) wsum[wid] = x;
  __syncthreads();
  int wb = 0;
  for (int w = 0; w < wid; ++w) wb += wsum[w];
  int ex = wb + x - ts;
  cur[2 * t] = ex;
  cur[2 * t + 1] = ex + v0;
  int n0 = (bkt << 9) + 2 * t, n1 = n0 + 1;
  if (n0 < nN) { off[n0] = start + ex;      deg[n0] = v0; }
  if (n1 < nN) { off[n1] = start + ex + v0; deg[n1] = v1; }
  __syncthreads();
  for (int i = start + t; i < end; i += 256) {
    uint e = tmp[i];
    int r = atomicAdd(&cur[e >> 17], 1);
    esrc[start + r] = (int)(e & 0x1FFFFu);
  }
}

// ---------------- gather 1 (fp8 in, bf16 out, 128-dim rows) -----------------
// one 16-lane group per node; lane owns a fixed 8-byte feature slice; edges
// iterate serially with unroll-8 (32 row-loads in flight per wave); zero
// cross-lane reduction in the epilogue.
__global__ __launch_bounds__(256) void gather1_kernel(
    const uchar* __restrict__ x8, const int* __restrict__ esrc,
    const int* __restrict__ off, const int* __restrict__ deg,
    ushort* __restrict__ aggm, int nN) {
  const int w = (blockIdx.x * blockDim.x + threadIdx.x) >> 4;
  const int l = threadIdx.x & 15;
  if (w >= nN) return;
  const int o = off[w];
  const int d = deg[w];
  const uint2* __restrict__ xp = (const uint2*)x8;  // row s at xp + s*16
  f32x2 a0 = {}, a1 = {}, a2 = {}, a3 = {};
  int i = 0;
  for (; i + 8 <= d; i += 8) {
    int s0 = esrc[o + i + 0], s1 = esrc[o + i + 1];
    int s2 = esrc[o + i + 2], s3 = esrc[o + i + 3];
    int s4 = esrc[o + i + 4], s5 = esrc[o + i + 5];
    int s6 = esrc[o + i + 6], s7 = esrc[o + i + 7];
    uint2 v0 = xp[(size_t)s0 * 16 + l];
    uint2 v1 = xp[(size_t)s1 * 16 + l];
    uint2 v2 = xp[(size_t)s2 * 16 + l];
    uint2 v3 = xp[(size_t)s3 * 16 + l];
    uint2 v4 = xp[(size_t)s4 * 16 + l];
    uint2 v5 = xp[(size_t)s5 * 16 + l];
    uint2 v6 = xp[(size_t)s6 * 16 + l];
    uint2 v7 = xp[(size_t)s7 * 16 + l];
    a0 += ((__builtin_amdgcn_cvt_pk_f32_fp8(v0.x, false) +
            __builtin_amdgcn_cvt_pk_f32_fp8(v1.x, false)) +
           (__builtin_amdgcn_cvt_pk_f32_fp8(v2.x, false) +
            __builtin_amdgcn_cvt_pk_f32_fp8(v3.x, false))) +
          ((__builtin_amdgcn_cvt_pk_f32_fp8(v4.x, false) +
            __builtin_amdgcn_cvt_pk_f32_fp8(v5.x, false)) +
           (__builtin_amdgcn_cvt_pk_f32_fp8(v6.x, false) +
            __builtin_amdgcn_cvt_pk_f32_fp8(v7.x, false)));
    a1 += ((__builtin_amdgcn_cvt_pk_f32_fp8(v0.x, true) +
            __builtin_amdgcn_cvt_pk_f32_fp8(v1.x, true)) +
           (__builtin_amdgcn_cvt_pk_f32_fp8(v2.x, true) +
            __builtin_amdgcn_cvt_pk_f32_fp8(v3.x, true))) +
          ((__builtin_amdgcn_cvt_pk_f32_fp8(v4.x, true) +
            __builtin_amdgcn_cvt_pk_f32_fp8(v5.x, true)) +
           (__builtin_amdgcn_cvt_pk_f32_fp8(v6.x, true) +
            __builtin_amdgcn_cvt_pk_f32_fp8(v7.x, true)));
    a2 += ((__builtin_amdgcn_cvt_pk_f32_fp8(v0.y, false) +
            __builtin_amdgcn_cvt_pk_f32_fp8(v1.y, false)) +
           (__builtin_amdgcn_cvt_pk_f32_fp8(v2.y, false) +
            __builtin_amdgcn_cvt_pk_f32_fp8(v3.y, false))) +
          ((__builtin_amdgcn_cvt_pk_f32_fp8(v4.y, false) +
            __builtin_amdgcn_cvt_pk_f32_fp8(v5.y, false)) +
           (__builtin_amdgcn_cvt_pk_f32_fp8(v6.y, false) +
            __builtin_amdgcn_cvt_pk_f32_fp8(v7.y, false)));
    a3 += ((__builtin_amdgcn_cvt_pk_f32_fp8(v0.y, true) +
            __builtin_amdgcn_cvt_pk_f32_fp8(v1.y, true)) +
           (__builtin_amdgcn_cvt_pk_f32_fp8(v2.y, true) +
            __builtin_amdgcn_cvt_pk_f32_fp8(v3.y, true))) +
          ((__builtin_amdgcn_cvt_pk_f32_fp8(v4.y, true) +
            __builtin_amdgcn_cvt_pk_f32_fp8(v5.y, true)) +
           (__builtin_amdgcn_cvt_pk_f32_fp8(v6.y, true) +
            __builtin_amdgcn_cvt_pk_f32_fp8(v7.y, true)));
  }
  for (; i + 4 <= d; i += 4) {
    int s0 = esrc[o + i + 0], s1 = esrc[o + i + 1];
    int s2 = esrc[o + i + 2], s3 = esrc[o + i + 3];
    uint2 v0 = xp[(size_t)s0 * 16 + l];
    uint2 v1 = xp[(size_t)s1 * 16 + l];
    uint2 v2 = xp[(size_t)s2 * 16 + l];
    uint2 v3 = xp[(size_t)s3 * 16 + l];
    a0 += (__builtin_amdgcn_cvt_pk_f32_fp8(v0.x, false) +
           __builtin_amdgcn_cvt_pk_f32_fp8(v1.x, false)) +
          (__builtin_amdgcn_cvt_pk_f32_fp8(v2.x, false) +
           __builtin_amdgcn_cvt_pk_f32_fp8(v3.x, false));
    a1 += (__builtin_amdgcn_cvt_pk_f32_fp8(v0.x, true) +
           __builtin_amdgcn_cvt_pk_f32_fp8(v1.x, true)) +
          (__builtin_amdgcn_cvt_pk_f32_fp8(v2.x, true) +
           __builtin_amdgcn_cvt_pk_f32_fp8(v3.x, true));
    a2 += (__builtin_amdgcn_cvt_pk_f32_fp8(v0.y, false) +
           __builtin_amdgcn_cvt_pk_f32_fp8(v1.y, false)) +
          (__builtin_amdgcn_cvt_pk_f32_fp8(v2.y, false) +
           __builtin_amdgcn_cvt_pk_f32_fp8(v3.y, false));
    a3 += (__builtin_amdgcn_cvt_pk_f32_fp8(v0.y, true) +
           __builtin_amdgcn_cvt_pk_f32_fp8(v1.y, true)) +
          (__builtin_amdgcn_cvt_pk_f32_fp8(v2.y, true) +
           __builtin_amdgcn_cvt_pk_f32_fp8(v3.y, true));
  }
  for (; i < d; ++i) {
    int s = esrc[o + i];
    uint2 v = xp[(size_t)s * 16 + l];
    a0 += __builtin_amdgcn_cvt_pk_f32_fp8(v.x, false);
    a1 += __builtin_amdgcn_cvt_pk_f32_fp8(v.x, true);
    a2 += __builtin_amdgcn_cvt_pk_f32_fp8(v.y, false);
    a3 += __builtin_amdgcn_cvt_pk_f32_fp8(v.y, true);
  }
  float inv = 1.0f / fmaxf((float)d, 1.0f);
  uint4 ov;
  ov.x = (uint)f2b(a0.x * inv) | ((uint)f2b(a0.y * inv) << 16);
  ov.y = (uint)f2b(a1.x * inv) | ((uint)f2b(a1.y * inv) << 16);
  ov.z = (uint)f2b(a2.x * inv) | ((uint)f2b(a2.y * inv) << 16);
  ov.w = (uint)f2b(a3.x * inv) | ((uint)f2b(a3.y * inv) << 16);
  ((uint4*)(aggm + (size_t)w * NF))[l] = ov;
}

// ---------------- gather 2 (fp8 in, fp32 out, 64-dim rows, permuted) --------
// one 8-lane group per node; lane owns 8 bytes; identity byte->float mapping
// so the permuted z8 layout carries straight through to aggz.
__global__ __launch_bounds__(256) void gather2_kernel(
    const uchar* __restrict__ z8, const int* __restrict__ esrc,
    const int* __restrict__ off, const int* __restrict__ deg,
    float* __restrict__ aggz, int nN) {
  const int w = (blockIdx.x * blockDim.x + threadIdx.x) >> 3;
  const int l = threadIdx.x & 7;
  if (w >= nN) return;
  const int o = off[w];
  const int d = deg[w];
  const uint2* __restrict__ zp = (const uint2*)z8;  // row s at zp + s*8
  f32x2 a0 = {}, a1 = {}, a2 = {}, a3 = {};
  int i = 0;
  for (; i + 8 <= d; i += 8) {
    int s0 = esrc[o + i + 0], s1 = esrc[o + i + 1];
    int s2 = esrc[o + i + 2], s3 = esrc[o + i + 3];
    int s4 = esrc[o + i + 4], s5 = esrc[o + i + 5];
    int s6 = esrc[o + i + 6], s7 = esrc[o + i + 7];
    uint2 v0 = zp[(size_t)s0 * 8 + l];
    uint2 v1 = zp[(size_t)s1 * 8 + l];
    uint2 v2 = zp[(size_t)s2 * 8 + l];
    uint2 v3 = zp[(size_t)s3 * 8 + l];
    uint2 v4 = zp[(size_t)s4 * 8 + l];
    uint2 v5 = zp[(size_t)s5 * 8 + l];
    uint2 v6 = zp[(size_t)s6 * 8 + l];
    uint2 v7 = zp[(size_t)s7 * 8 + l];
    a0 += ((__builtin_amdgcn_cvt_pk_f32_fp8(v0.x, false) +
            __builtin_amdgcn_cvt_pk_f32_fp8(v1.x, false)) +
           (__builtin_amdgcn_cvt_pk_f32_fp8(v2.x, false) +
            __builtin_amdgcn_cvt_pk_f32_fp8(v3.x, false))) +
          ((__builtin_amdgcn_cvt_pk_f32_fp8(v4.x, false) +
            __builtin_amdgcn_cvt_pk_f32_fp8(v5.x, false)) +
           (__builtin_amdgcn_cvt_pk_f32_fp8(v6.x, false) +
            __builtin_amdgcn_cvt_pk_f32_fp8(v7.x, false)));
    a1 += ((__builtin_amdgcn_cvt_pk_f32_fp8(v0.x, true) +
            __builtin_amdgcn_cvt_pk_f32_fp8(v1.x, true)) +
           (__builtin_amdgcn_cvt_pk_f32_fp8(v2.x, true) +
            __builtin_amdgcn_cvt_pk_f32_fp8(v3.x, true))) +
          ((__builtin_amdgcn_cvt_pk_f32_fp8(v4.x, true) +
            __builtin_amdgcn_cvt_pk_f32_fp8(v5.x, true)) +
           (__builtin_amdgcn_cvt_pk_f32_fp8(v6.x, true) +
            __builtin_amdgcn_cvt_pk_f32_fp8(v7.x, true)));
    a2 += ((__builtin_amdgcn_cvt_pk_f32_fp8(v0.y, false) +
            __builtin_amdgcn_cvt_pk_f32_fp8(v1.y, false)) +
           (__builtin_amdgcn_cvt_pk_f32_fp8(v2.y, false) +
            __builtin_amdgcn_cvt_pk_f32_fp8(v3.y, false))) +
          ((__builtin_amdgcn_cvt_pk_f32_fp8(v4.y, false) +
            __builtin_amdgcn_cvt_pk_f32_fp8(v5.y, false)) +
           (__builtin_amdgcn_cvt_pk_f32_fp8(v6.y, false) +
            __builtin_amdgcn_cvt_pk_f32_fp8(v7.y, false)));
    a3 += ((__builtin_amdgcn_cvt_pk_f32_fp8(v0.y, true) +
            __builtin_amdgcn_cvt_pk_f32_fp8(v1.y, true)) +
           (__builtin_amdgcn_cvt_pk_f32_fp8(v2.y, true) +
            __builtin_amdgcn_cvt_pk_f32_fp8(v3.y, true))) +
          ((__builtin_amdgcn_cvt_pk_f32_fp8(v4.y, true) +
            __builtin_amdgcn_cvt_pk_f32_fp8(v5.y, true)) +
           (__builtin_amdgcn_cvt_pk_f32_fp8(v6.y, true) +
            __builtin_amdgcn_cvt_pk_f32_fp8(v7.y, true)));
  }
  for (; i + 4 <= d; i += 4) {
    int s0 = esrc[o + i + 0], s1 = esrc[o + i + 1];
    int s2 = esrc[o + i + 2], s3 = esrc[o + i + 3];
    uint2 v0 = zp[(size_t)s0 * 8 + l];
    uint2 v1 = zp[(size_t)s1 * 8 + l];
    uint2 v2 = zp[(size_t)s2 * 8 + l];
    uint2 v3 = zp[(size_t)s3 * 8 + l];
    a0 += (__builtin_amdgcn_cvt_pk_f32_fp8(v0.x, false) +
           __builtin_amdgcn_cvt_pk_f32_fp8(v1.x, false)) +
          (__builtin_amdgcn_cvt_pk_f32_fp8(v2.x, false) +
           __builtin_amdgcn_cvt_pk_f32_fp8(v3.x, false));
    a1 += (__builtin_amdgcn_cvt_pk_f32_fp8(v0.x, true) +
           __builtin_amdgcn_cvt_pk_f32_fp8(v1.x, true)) +
          (__builtin_amdgcn_cvt_pk_f32_fp8(v2.x, true) +
           __builtin_amdgcn_cvt_pk_f32_fp8(v3.x, true));
    a2 += (__builtin_amdgcn_cvt_pk_f32_fp8(v0.y, false) +
           __builtin_amdgcn_cvt_pk_f32_fp8(v1.y, false)) +
          (__builtin_amdgcn_cvt_pk_f32_fp8(v2.y, false) +
           __builtin_amdgcn_cvt_pk_f32_fp8(v3.y, false));
    a3 += (__builtin_amdgcn_cvt_pk_f32_fp8(v0.y, true) +
           __builtin_amdgcn_cvt_pk_f32_fp8(v1.y, true)) +
          (__builtin_amdgcn_cvt_pk_f32_fp8(v2.y, true) +
           __builtin_amdgcn_cvt_pk_f32_fp8(v3.y, true));
  }
  for (; i < d; ++i) {
    int s = esrc[o + i];
    uint2 v = zp[(size_t)s * 8 + l];
    a0 += __builtin_amdgcn_cvt_pk_f32_fp8(v.x, false);
    a1 += __builtin_amdgcn_cvt_pk_f32_fp8(v.x, true);
    a2 += __builtin_amdgcn_cvt_pk_f32_fp8(v.y, false);
    a3 += __builtin_amdgcn_cvt_pk_f32_fp8(v.y, true);
  }
  float inv = 1.0f / fmaxf((float)d, 1.0f);
  ((float4*)(aggz + (size_t)w * NC))[2 * l] =
      make_float4(a0.x * inv, a0.y * inv, a1.x * inv, a1.y * inv);
  ((float4*)(aggz + (size_t)w * NC))[2 * l + 1] =
      make_float4(a2.x * inv, a2.y * inv, a3.x * inv, a3.y * inv);
}

// ---------------- fused layer 1 + 2a (MFMA) ---------------------------------
// h = relu([mean||x] @ W1cat + b1)   -> hb (global, bf16) and LDS band
// z = h @ W2l^T                      -> z8 (fp8, permuted layout)
__global__ __launch_bounds__(256) void layer12_mfma(
    const ushort* __restrict__ xb, const ushort* __restrict__ aggb,
    const ushort* __restrict__ Wp1, const float* __restrict__ b1,
    const ushort* __restrict__ Wp2l,
    ushort* __restrict__ hb, uchar* __restrict__ z8, int nN) {
  const int t = threadIdx.x;
  const int wv = t >> 6;
  const int lane = t & 63;
  const int base = blockIdx.x * 64;
  __shared__ ushort As[64][264];  // 256 cols + 8 pad
  for (int i = t; i < 64 * 32; i += 256) {
    int r = i >> 5, cq = i & 31;
    int node = base + r;
    short8 v = {};
    if (node < nN) {
      const ushort* sp = (cq < 16) ? (aggb + (size_t)node * NF + cq * 8)
                                   : (xb + (size_t)node * NF + (cq - 16) * 8);
      v = *(const short8*)sp;
    }
    *(short8*)&As[r][cq * 8] = v;
  }
  __syncthreads();

  f32x4 acc[8] = {};
  const int arow = wv * 16 + (lane & 15);
  const int kq = (lane >> 4) * 8;
#pragma unroll
  for (int kt = 0; kt < 8; ++kt) {
    short8 af = *(const short8*)&As[arow][kt * 32 + kq];
#pragma unroll
    for (int nt = 0; nt < 8; ++nt) {
      short8 bf = *(const short8*)(Wp1 + ((size_t)(kt * 8 + nt) * 64 + lane) * 8);
      acc[nt] = __builtin_amdgcn_mfma_f32_16x16x32_bf16(af, bf, acc[nt], 0, 0, 0);
    }
  }
  const int quad = lane >> 4;
  const int cl = lane & 15;
#pragma unroll
  for (int nt = 0; nt < 8; ++nt) {
    float bj = b1[nt * 16 + cl];
#pragma unroll
    for (int r = 0; r < 4; ++r) {
      int node = base + wv * 16 + quad * 4 + r;
      ushort hv = f2b(fmaxf(acc[nt][r] + bj, 0.0f));
      As[wv * 16 + quad * 4 + r][nt * 16 + cl] = hv;  // wave-private band
      if (node < nN) hb[(size_t)node * NF + nt * 16 + cl] = hv;
    }
  }

  // ---- stage 2: z = h @ W2l^T (reads only this wave's own LDS band) ----
  f32x4 acc2[4] = {};
#pragma unroll
  for (int kt = 0; kt < 4; ++kt) {
    short8 af = *(const short8*)&As[arow][kt * 32 + kq];
#pragma unroll
    for (int nt = 0; nt < 4; ++nt) {
      short8 bf = *(const short8*)(Wp2l + ((size_t)(kt * 4 + nt) * 64 + lane) * 8);
      acc2[nt] = __builtin_amdgcn_mfma_f32_16x16x32_bf16(af, bf, acc2[nt], 0, 0, 0);
    }
  }
#pragma unroll
  for (int r = 0; r < 4; ++r) {
    int node = base + wv * 16 + quad * 4 + r;
    if (node < nN) {
      int u = __builtin_amdgcn_cvt_pk_fp8_f32(acc2[0][r], acc2[1][r], 0, false);
      u = __builtin_amdgcn_cvt_pk_fp8_f32(acc2[2][r], acc2[3][r], u, true);
      ((uint*)(z8 + (size_t)node * NC))[cl] = (uint)u;
    }
  }
}

// ---------------- layer 2b (MFMA): out = logsoftmax(aggz + h@W2r^T + b) -----
__global__ __launch_bounds__(256) void layer2b_mfma(
    const ushort* __restrict__ hb, const float* __restrict__ aggz,
    const ushort* __restrict__ Wp, const float* __restrict__ b2,
    float* __restrict__ out, int nN) {
  const int t = threadIdx.x;
  const int wv = t >> 6;
  const int lane = t & 63;
  const int base = blockIdx.x * 64;
  __shared__ ushort As[64][136];
  for (int i = t; i < 64 * 16; i += 256) {
    int r = i >> 4, cq = i & 15;
    int node = base + r;
    short8 v = {};
    if (node < nN) v = *(const short8*)(hb + (size_t)node * NF + cq * 8);
    *(short8*)&As[r][cq * 8] = v;
  }
  __syncthreads();

  f32x4 acc[4] = {};
  const int arow = wv * 16 + (lane & 15);
  const int kq = (lane >> 4) * 8;
#pragma unroll
  for (int kt = 0; kt < 4; ++kt) {
    short8 af = *(const short8*)&As[arow][kt * 32 + kq];
#pragma unroll
    for (int nt = 0; nt < 4; ++nt) {
      short8 bf = *(const short8*)(Wp + ((size_t)(kt * 4 + nt) * 64 + lane) * 8);
      acc[nt] = __builtin_amdgcn_mfma_f32_16x16x32_bf16(af, bf, acc[nt], 0, 0, 0);
    }
  }
  const int quad = lane >> 4;
  const int cl = lane & 15;
  float bj[4];
#pragma unroll
  for (int nt = 0; nt < 4; ++nt) bj[nt] = b2[nt * 16 + cl];

#pragma unroll
  for (int r = 0; r < 4; ++r) {
    int node = base + wv * 16 + quad * 4 + r;
    int nvalid = (node < nN);
    float a0 = 0.f, a1 = 0.f, a2 = 0.f, a3 = 0.f;
    if (nvalid) {
      // aggz is in the permuted layout: float4 at [cl] = cols {nt*16+cl}
      float4 av = ((const float4*)(aggz + (size_t)node * NC))[cl];
      a0 = av.x; a1 = av.y; a2 = av.z; a3 = av.w;
    }
    float v0 = acc[0][r] + bj[0] + a0;
    float v1 = acc[1][r] + bj[1] + a1;
    float v2 = acc[2][r] + bj[2] + a2;
    float v3 = acc[3][r] + bj[3] + a3;
    float mx = fmaxf(fmaxf(v0, v1), fmaxf(v2, v3));
#pragma unroll
    for (int s = 1; s < 16; s <<= 1) mx = fmaxf(mx, __shfl_xor(mx, s));
    float sm = expf(v0 - mx) + expf(v1 - mx) + expf(v2 - mx) + expf(v3 - mx);
#pragma unroll
    for (int s = 1; s < 16; s <<= 1) sm += __shfl_xor(sm, s);
    float ls = mx + logf(sm);
    if (nvalid) {
      float* op = out + (size_t)node * NC;
      op[0 * 16 + cl] = v0 - ls;
      op[1 * 16 + cl] = v1 - ls;
      op[2 * 16 + cl] = v2 - ls;
      op[3 * 16 + cl] = v3 - ls;
    }
  }
}

extern "C" void kernel_launch(void* const* d_in, const int* in_sizes, int n_in,
                              void* d_out, int out_size, void* d_ws, size_t ws_size,
                              hipStream_t stream) {
  const float* x   = (const float*)d_in[0];
  const int*   ei  = (const int*)d_in[1];
  const float* W1l = (const float*)d_in[2];
  const float* b1l = (const float*)d_in[3];
  const float* W1r = (const float*)d_in[4];
  const float* W2l = (const float*)d_in[5];
  const float* b2l = (const float*)d_in[6];
  const float* W2r = (const float*)d_in[7];
  float* out = (float*)d_out;

  const int nN = in_sizes[0] / NF;  // 100000
  const int nE = in_sizes[1] / 2;   // 1600000
  const int* src = ei;
  const int* dst = ei + nE;

  char* p = (char*)d_ws;
  ushort* xb   = (ushort*)p; p += (size_t)nN * NF * 2;
  ushort* hb   = (ushort*)p; p += (size_t)nN * NF * 2;   // first half doubles as x8
  ushort* aggb = (ushort*)p; p += (size_t)nN * NF * 2;   // reused as aggz (fp32, same bytes)
  ushort* Wp1  = (ushort*)p; p += 256 * 128 * 2;
  ushort* Wp2l = (ushort*)p; p += 128 * 64 * 2;
  ushort* Wp2r = (ushort*)p; p += 128 * 64 * 2;
  int* cntA = (int*)p; p += (size_t)NBKT * NBA * 4;
  int* cntS = (int*)p; p += (size_t)NBKT * NBA * 4;
  int* bsum = (int*)p; p += 512;
  int* deg  = (int*)p; p += (size_t)nN * 4;
  int* off  = (int*)p; p += (size_t)nN * 4;
  int* esrc = (int*)p; p += (size_t)nE * 4;
  uint* tmp = (uint*)p; p += (size_t)nE * 4;             // doubles as z8 after bsortB

  uchar* x8   = (uchar*)hb;     // alias: hb written only in layer12, after gather1
  uchar* z8   = (uchar*)tmp;    // alias: tmp dead after bsortB
  float* aggz = (float*)aggb;   // alias: aggb dead after layer12

  const int n4 = nN * NF / 4;
  const int nb_cast = (n4 + 255) / 256;
  const int epb = (nE + NBA - 1) / NBA;
  const int L = NBKT * NBA;
  const int nbL = (L + 1023) / 1024;

  // prep (casts + weight packs) + edge histogram fused into one launch
  prep_kernel<<<nb_cast + 192 + NBA, 256, 0, stream>>>(
      x, xb, x8, n4, nb_cast, W1l, W1r, Wp1, W2l, W2r, Wp2l, Wp2r,
      dst, cntA, nE, epb);

  // --- CSR build: atomic-free (LDS-only ranks) two-pass bucket sort ---
  scanL1_kernel<<<nbL, 256, 0, stream>>>(cntA, cntS, bsum, L);
  bscatA_kernel<<<NBA, 256, 0, stream>>>(src, dst, cntS, bsum, tmp, nE, epb, nbL);
  bsortB_kernel<<<NBKT, 256, 0, stream>>>(tmp, cntS, bsum, esrc, deg, off, nN, nE, nbL);

  // --- layer 1 + 2a ---
  gather1_kernel<<<(nN * 16 + 255) / 256, 256, 0, stream>>>(x8, esrc, off, deg, aggb, nN);
  layer12_mfma<<<(nN + 63) / 64, 256, 0, stream>>>(xb, aggb, Wp1, b1l, Wp2l, hb, z8, nN);

  // --- layer 2 (projection-first: mean of z, then +h@W2r) ---
  gather2_kernel<<<(nN * 8 + 255) / 256, 256, 0, stream>>>(z8, esrc, off, deg, aggz, nN);
  layer2b_mfma<<<(nN + 63) / 64, 256, 0, stream>>>(hb, aggz, Wp2r, b2l, out, nN);
}